// Round 1
// baseline (189.743 us; speedup 1.0000x reference)
//
#include <hip/hip_runtime.h>

#define N_PIX 65536
#define W_IMG 256
#define M_GT  512
#define NB    4

constexpr float EPS   = 1e-6f;
// max_dist = sqrt(256^2 + 256^2) = 362.03867196751236 (double, rounded to f32 at use)
constexpr float MAXD  = 362.03867196751236f;
// float(EPS / max_dist) computed in double like the reference
constexpr float C_DEN = 2.7621343e-09f;
#define BIGF 3.0e38f

// ---------------- init: set per-gt min slots to +inf ----------------
__global__ void whd_init(unsigned int* __restrict__ minval) {
  int i = blockIdx.x * blockDim.x + threadIdx.x;
  if (i < NB * M_GT) minval[i] = 0x7F800000u;  // +inf bits
}

// ---------------- main pair loop ----------------
// grid: (64 row-tiles, NB samples), block: 256 threads (one per column)
// each thread owns 4 consecutive rows at its column -> dx^2 shared per gt
__global__ __launch_bounds__(256) void whd_pairs(
    const float* __restrict__ prob, const int* __restrict__ gt,
    unsigned int* __restrict__ minval, float2* __restrict__ partials)
{
  const int b    = blockIdx.y;
  const int tile = blockIdx.x;     // 0..63 -> rows [tile*4, tile*4+4)
  const int tid  = threadIdx.x;    // column 0..255
  const int lane = tid & 63;
  const int wave = tid >> 6;

  __shared__ float2 gl[M_GT];          // (gy, gx) as floats
  __shared__ float  wmin[4][M_GT];     // wave-private per-gt min
  __shared__ float  r1[256], r0[256];  // term1 partial reduce

  const int2* gtb = (const int2*)(gt + b * M_GT * 2);
  for (int j = tid; j < M_GT; j += 256) {
    int2 g = gtb[j];
    gl[j] = make_float2((float)g.x, (float)g.y);  // g.x = row(y), g.y = col(x)
  }

  const float xf   = (float)tid;
  const int   row0 = tile * 4;
  const float* pb  = prob + b * N_PIX;

  float p[4], w[4], ew[4], yf[4], mind2[4];
#pragma unroll
  for (int k = 0; k < 4; ++k) {
    p[k]  = pb[(row0 + k) * W_IMG + tid];   // coalesced across tid
    yf[k] = (float)(row0 + k);
    float p2    = p[k] * p[k];
    float denom = p2 * p2 + C_DEN;          // p^4 + eps/max_dist
    w[k]  = 1.0f / denom;
    ew[k] = EPS * w[k];
    mind2[k] = BIGF;
  }
  __syncthreads();

  for (int j = 0; j < M_GT; ++j) {
    float2 g  = gl[j];                 // broadcast read, no bank conflict
    float dx  = xf - g.y;
    float dx2 = dx * dx;
    float v   = BIGF;
#pragma unroll
    for (int k = 0; k < 4; ++k) {
      float dy = yf[k] - g.x;
      float d2 = fmaf(dy, dy, dx2);    // exact: integer-valued, < 2^24
      mind2[k] = fminf(mind2[k], d2);  // term 1: min over gt of d^2
      float d   = __builtin_amdgcn_sqrtf(d2);
      float val = fmaf(d, w[k], ew[k]);  // (d+eps)/(p^4+eps/maxd)
      v = fminf(v, val);
    }
    // term 2: min over this wave's 256 pixels for gt j
#pragma unroll
    for (int m = 1; m < 64; m <<= 1) v = fminf(v, __shfl_xor(v, m, 64));
    if (lane == 0) wmin[wave][j] = v;
  }
  __syncthreads();

  // cross-wave min, then exact (deterministic) global atomic min
  for (int j = tid; j < M_GT; j += 256) {
    float v = fminf(fminf(wmin[0][j], wmin[1][j]),
                    fminf(wmin[2][j], wmin[3][j]));
    atomicMin(minval + b * M_GT + j, __float_as_uint(v));  // v >= 0: bit order ok
  }

  // term 1 partials: sum p * sqrt(min d^2), sum p
  float s1 = 0.f, s0 = 0.f;
#pragma unroll
  for (int k = 0; k < 4; ++k) {
    s1 += p[k] * __builtin_amdgcn_sqrtf(mind2[k]);
    s0 += p[k];
  }
  r1[tid] = s1; r0[tid] = s0;
  __syncthreads();
  for (int s = 128; s > 0; s >>= 1) {
    if (tid < s) { r1[tid] += r1[tid + s]; r0[tid] += r0[tid + s]; }
    __syncthreads();
  }
  if (tid == 0) partials[b * 64 + tile] = make_float2(r1[0], r0[0]);
}

// ---------------- finalize: deterministic reduction ----------------
__global__ __launch_bounds__(256) void whd_final(
    const unsigned int* __restrict__ minval,
    const float2* __restrict__ partials,
    float* __restrict__ out)
{
  const int tid  = threadIdx.x;
  const int lane = tid & 63;
  const int b    = tid >> 6;   // one wave per sample
  __shared__ float t1[NB], t2[NB];

  // term 2: mean of clipped per-gt mins
  float s2 = 0.f;
  for (int j = lane; j < M_GT; j += 64) {
    float v = __uint_as_float(minval[b * M_GT + j]);
    v = fminf(fmaxf(v, 0.f), MAXD);
    s2 += v;
  }
  // term 1: 64 per-tile partials, one per lane
  float2 pp = partials[b * 64 + lane];
  float s1 = pp.x, s0 = pp.y;
#pragma unroll
  for (int m = 1; m < 64; m <<= 1) {
    s2 += __shfl_xor(s2, m, 64);
    s1 += __shfl_xor(s1, m, 64);
    s0 += __shfl_xor(s0, m, 64);
  }
  if (lane == 0) {
    t1[b] = s1 / (s0 + EPS);
    t2[b] = s2 / (float)M_GT;
  }
  __syncthreads();
  if (tid == 0) {
    float a = 0.f, c = 0.f;
    for (int i = 0; i < NB; ++i) { a += t1[i]; c += t2[i]; }
    out[0] = a * 0.25f + c * 0.25f;
  }
}

extern "C" void kernel_launch(void* const* d_in, const int* in_sizes, int n_in,
                              void* d_out, int out_size, void* d_ws, size_t ws_size,
                              hipStream_t stream) {
  const float* prob = (const float*)d_in[0];
  const int*   gt   = (const int*)d_in[1];

  unsigned int* minval   = (unsigned int*)d_ws;
  float2*       partials = (float2*)((char*)d_ws + (size_t)NB * M_GT * sizeof(unsigned int));

  whd_init<<<(NB * M_GT + 255) / 256, 256, 0, stream>>>(minval);
  whd_pairs<<<dim3(64, NB), 256, 0, stream>>>(prob, gt, minval, partials);
  whd_final<<<1, 256, 0, stream>>>(minval, partials, (float*)d_out);
}

// Round 2
// 57.693 us; speedup vs baseline: 3.2889x; 3.2889x over previous
//
#include <hip/hip_runtime.h>

#define W_IMG 256
#define H_IMG 256
#define N_PIX 65536
#define M_GT  512
#define NB    4

constexpr float EPS   = 1e-6f;
constexpr float MAXD  = 362.03867196751236f;
constexpr float C_DEN = 2.7621343e-09f;   // float(EPS / max_dist)
#define BIGF 3.0e38f

// ---------------- init: per-gt min slots = +inf ----------------
__global__ void whd_init(unsigned int* __restrict__ minval) {
  int i = blockIdx.x * blockDim.x + threadIdx.x;
  if (i < NB * M_GT) minval[i] = 0x7F800000u;
}

// ---------------- pair kernel, role split by blockIdx.x parity ----------------
// grid: (512, NB). row = blockIdx.x >> 1. role = blockIdx.x & 1.
// Role 0 (term 1): thread = pixel (row, tid); loop gt from LDS; thread-local min d^2.
// Role 1 (term 2): thread owns gt {tid, tid+256}; loop 256 pixels of `row` from LDS;
//                  thread-local min of (d+eps)*w; exact atomicMin at end.
__global__ __launch_bounds__(256) void whd_pairs(
    const float* __restrict__ prob, const int* __restrict__ gt,
    unsigned int* __restrict__ minval, float2* __restrict__ partials)
{
  const int b   = blockIdx.y;
  const int row = blockIdx.x >> 1;
  const int tid = threadIdx.x;
  const int2* gtb = (const int2*)(gt + b * M_GT * 2);

  if ((blockIdx.x & 1) == 0) {
    // ---------------- term 1 ----------------
    __shared__ float2 gl[M_GT];       // (gx, dy^2) for this row
    __shared__ float ws1[4], ws0[4];
    const float yf = (float)row;
    for (int j = tid; j < M_GT; j += 256) {
      int2 g = gtb[j];                // g.x = row(y), g.y = col(x)
      float dy = yf - (float)g.x;
      gl[j] = make_float2((float)g.y, dy * dy);  // dy^2 exact (int < 2^24)
    }
    __syncthreads();

    const float xf = (float)tid;
    const float p  = prob[b * N_PIX + row * W_IMG + tid];
    float m0 = BIGF, m1 = BIGF;
#pragma unroll 8
    for (int j = 0; j < M_GT; j += 2) {
      float2 g0 = gl[j];              // broadcast reads
      float2 g1 = gl[j + 1];
      float dx0 = xf - g0.x;
      m0 = fminf(m0, fmaf(dx0, dx0, g0.y));   // d^2 exact (< 2^24)
      float dx1 = xf - g1.x;
      m1 = fminf(m1, fmaf(dx1, dx1, g1.y));
    }
    float d  = __builtin_amdgcn_sqrtf(fminf(m0, m1));
    float s1 = p * d, s0 = p;
#pragma unroll
    for (int m = 1; m < 64; m <<= 1) {
      s1 += __shfl_xor(s1, m, 64);
      s0 += __shfl_xor(s0, m, 64);
    }
    const int lane = tid & 63, wave = tid >> 6;
    if (lane == 0) { ws1[wave] = s1; ws0[wave] = s0; }
    __syncthreads();
    if (tid == 0) {
      float a = ws1[0] + ws1[1] + ws1[2] + ws1[3];
      float c = ws0[0] + ws0[1] + ws0[2] + ws0[3];
      partials[b * H_IMG + row] = make_float2(a, c);
    }
  } else {
    // ---------------- term 2 ----------------
    __shared__ float4 pix[W_IMG];     // (py, px, w, ew)
    {
      float p  = prob[b * N_PIX + row * W_IMG + tid];
      float p2 = p * p;
      float denom = p2 * p2 + C_DEN; // p^4 + eps/max_dist
      float w  = 1.0f / denom;
      pix[tid] = make_float4((float)row, (float)tid, w, EPS * w);
    }
    int2 g0 = gtb[tid];
    int2 g1 = gtb[tid + 256];
    const float gy0 = (float)g0.x, gx0 = (float)g0.y;
    const float gy1 = (float)g1.x, gx1 = (float)g1.y;
    float v0 = BIGF, v1 = BIGF;
    __syncthreads();

#pragma unroll 4
    for (int i = 0; i < W_IMG; ++i) {
      float4 q  = pix[i];             // broadcast read
      float dy0 = q.x - gy0, dx0 = q.y - gx0;
      float dA  = __builtin_amdgcn_sqrtf(fmaf(dy0, dy0, dx0 * dx0));
      v0 = fminf(v0, fmaf(dA, q.z, q.w));     // (d+eps)*w
      float dy1 = q.x - gy1, dx1 = q.y - gx1;
      float dB  = __builtin_amdgcn_sqrtf(fmaf(dy1, dy1, dx1 * dx1));
      v1 = fminf(v1, fmaf(dB, q.z, q.w));
    }
    atomicMin(minval + b * M_GT + tid,       __float_as_uint(v0));  // v >= 0
    atomicMin(minval + b * M_GT + tid + 256, __float_as_uint(v1));
  }
}

// ---------------- finalize: deterministic reduction ----------------
__global__ __launch_bounds__(256) void whd_final(
    const unsigned int* __restrict__ minval,
    const float2* __restrict__ partials,
    float* __restrict__ out)
{
  const int tid  = threadIdx.x;
  const int lane = tid & 63;
  const int b    = tid >> 6;        // one wave per sample
  __shared__ float t1[NB], t2[NB];

  // term 2: mean of clipped per-gt mins (8 per lane)
  float s2 = 0.f;
#pragma unroll
  for (int u = 0; u < M_GT / 64; ++u) {
    float v = __uint_as_float(minval[b * M_GT + u * 64 + lane]);
    v = fminf(fmaxf(v, 0.f), MAXD);
    s2 += v;
  }
  // term 1: 256 per-row partials (4 per lane)
  float s1 = 0.f, s0 = 0.f;
#pragma unroll
  for (int u = 0; u < H_IMG / 64; ++u) {
    float2 pp = partials[b * H_IMG + u * 64 + lane];
    s1 += pp.x; s0 += pp.y;
  }
#pragma unroll
  for (int m = 1; m < 64; m <<= 1) {
    s2 += __shfl_xor(s2, m, 64);
    s1 += __shfl_xor(s1, m, 64);
    s0 += __shfl_xor(s0, m, 64);
  }
  if (lane == 0) {
    t1[b] = s1 / (s0 + EPS);
    t2[b] = s2 / (float)M_GT;
  }
  __syncthreads();
  if (tid == 0) {
    float a = 0.f, c = 0.f;
    for (int i = 0; i < NB; ++i) { a += t1[i]; c += t2[i]; }
    out[0] = a * 0.25f + c * 0.25f;
  }
}

extern "C" void kernel_launch(void* const* d_in, const int* in_sizes, int n_in,
                              void* d_out, int out_size, void* d_ws, size_t ws_size,
                              hipStream_t stream) {
  const float* prob = (const float*)d_in[0];
  const int*   gt   = (const int*)d_in[1];

  unsigned int* minval   = (unsigned int*)d_ws;
  float2*       partials = (float2*)((char*)d_ws + (size_t)NB * M_GT * sizeof(unsigned int));

  whd_init<<<(NB * M_GT + 255) / 256, 256, 0, stream>>>(minval);
  whd_pairs<<<dim3(2 * H_IMG, NB), 256, 0, stream>>>(prob, gt, minval, partials);
  whd_final<<<1, 256, 0, stream>>>(minval, partials, (float*)d_out);
}

// Round 3
// 15.769 us; speedup vs baseline: 12.0326x; 3.6586x over previous
//
#include <hip/hip_runtime.h>

#define W_IMG 256
#define H_IMG 256
#define N_PIX 65536
#define M_GT  512
#define NB    4
#define TILES 256   // 16x16 grid of 16x16-pixel tiles

constexpr float EPS   = 1e-6f;
constexpr float MAXD  = 362.03867196751236f;
constexpr float C_DEN = 2.7621343e-09f;   // float(EPS / max_dist)
#define BIGF 3.0e38f

// ---------------- K1: term-1 tiles (blockIdx.x < 256) + term-2 pass A ----------------
__global__ __launch_bounds__(256) void whd_k1(
    const float* __restrict__ prob, const int* __restrict__ gt,
    float* __restrict__ minU, float2* __restrict__ partials)
{
  const int b    = blockIdx.y;
  const int tid  = threadIdx.x;
  const int lane = tid & 63;
  const int wave = tid >> 6;
  const int2* gtb = (const int2*)(gt + b * M_GT * 2);

  if (blockIdx.x < TILES) {
    // ---- term 1: one 16x16 pixel tile, candidate-pruned gt scan ----
    const int tile = blockIdx.x;
    const int row0 = (tile >> 4) << 4;
    const int col0 = (tile & 15) << 4;
    __shared__ float2 list[M_GT];
    __shared__ float  wred[4], ws1[4], ws0[4];
    __shared__ int    lcount;
    if (tid == 0) lcount = 0;

    int2 g0 = gtb[tid];
    int2 g1 = gtb[tid + 256];
    const float cy = row0 + 7.5f, cx = col0 + 7.5f;
    const float g0y = (float)g0.x, g0x = (float)g0.y;
    const float g1y = (float)g1.x, g1x = (float)g1.y;
    float dcy0 = g0y - cy, dcx0 = g0x - cx;
    float dcy1 = g1y - cy, dcx1 = g1x - cx;
    float d2c0 = fmaf(dcy0, dcy0, dcx0 * dcx0);   // exact: half-int grid < 2^18
    float d2c1 = fmaf(dcy1, dcy1, dcx1 * dcx1);
    float m = fminf(d2c0, d2c1);
#pragma unroll
    for (int s = 1; s < 64; s <<= 1) m = fminf(m, __shfl_xor(m, s, 64));
    if (lane == 0) wred[wave] = m;
    __syncthreads();                               // also orders lcount=0 before atomics
    float dmin2 = fminf(fminf(wred[0], wred[1]), fminf(wred[2], wred[3]));
    // gt can be argmin for some pixel in tile only if dcenter <= dmin_center + 2*diag
    float rT = __builtin_amdgcn_sqrtf(dmin2) + 21.3f;  // 2*10.6066 + margin
    float T  = rT * rT + 0.5f;                         // absolute margin >> all rounding

    bool pr0 = d2c0 <= T, pr1 = d2c1 <= T;
    unsigned long long m0 = __ballot(pr0);
    unsigned long long m1 = __ballot(pr1);
    int c0 = __popcll(m0), c1 = __popcll(m1);
    int base = 0;
    if (lane == 0) base = atomicAdd(&lcount, c0 + c1);
    base = __shfl(base, 0, 64);
    unsigned long long lt = (1ull << lane) - 1ull;
    if (pr0) list[base + __popcll(m0 & lt)]      = make_float2(g0y, g0x);
    if (pr1) list[base + c0 + __popcll(m1 & lt)] = make_float2(g1y, g1x);
    __syncthreads();
    const int ncand = lcount;

    const int py = row0 + (tid >> 4);
    const int px = col0 + (tid & 15);
    const float p  = prob[b * N_PIX + py * W_IMG + px];
    const float yf = (float)py, xf = (float)px;
    float md2 = BIGF;
    for (int c = 0; c < ncand; ++c) {
      float2 g = list[c];                       // broadcast read
      float dy = yf - g.x, dx = xf - g.y;
      md2 = fminf(md2, fmaf(dy, dy, dx * dx));  // exact integer d^2
    }
    float s1 = p * __builtin_amdgcn_sqrtf(md2);
    float s0 = p;
#pragma unroll
    for (int s = 1; s < 64; s <<= 1) {
      s1 += __shfl_xor(s1, s, 64);
      s0 += __shfl_xor(s0, s, 64);
    }
    if (lane == 0) { ws1[wave] = s1; ws0[wave] = s0; }
    __syncthreads();
    if (tid == 0)
      partials[b * TILES + tile] =
          make_float2(ws1[0] + ws1[1] + ws1[2] + ws1[3],
                      ws0[0] + ws0[1] + ws0[2] + ws0[3]);
  } else {
    // ---- term 2 pass A: one wave per gt, 16x16 neighborhood -> upper bound U ----
    const int j = (blockIdx.x - TILES) * 4 + wave;   // 128 blocks * 4 waves = 512 gt
    int2 g = gtb[j];
    const int gy = g.x, gx = g.y;
    float vmin = BIGF;
#pragma unroll
    for (int k = 0; k < 4; ++k) {
      int idx = k * 64 + lane;            // 0..255
      int oy  = (idx >> 4) - 8;           // -8..7
      int ox  = (idx & 15) - 8;
      int y = gy + oy, x = gx + ox;
      if ((unsigned)y < H_IMG && (unsigned)x < W_IMG) {
        float p   = prob[b * N_PIX + y * W_IMG + x];
        float p2  = p * p;
        float den = p2 * p2 + C_DEN;
        float w   = 1.0f / den;
        float fdy = (float)oy, fdx = (float)ox;
        float d   = __builtin_amdgcn_sqrtf(fmaf(fdy, fdy, fdx * fdx));
        vmin = fminf(vmin, fmaf(d, w, EPS * w));   // (d+eps)/(p^4+eps/maxd)
      }
    }
#pragma unroll
    for (int s = 1; s < 64; s <<= 1) vmin = fminf(vmin, __shfl_xor(vmin, s, 64));
    if (lane == 0) minU[b * M_GT + j] = vmin;      // sole owner: no atomic/init
  }
}

// ---------------- K2: term-2 pass B — exact refine within radius R(U) ----------------
__global__ __launch_bounds__(256) void whd_k2(
    const float* __restrict__ prob, const int* __restrict__ gt,
    float* __restrict__ minU)
{
  const int b    = blockIdx.y;
  const int tid  = threadIdx.x;
  const int lane = tid & 63;
  const int wave = tid >> 6;
  const int j    = blockIdx.x * 4 + wave;
  const int2* gtb = (const int2*)(gt + b * M_GT * 2);
  int2 g = gtb[j];
  const int gy = g.x, gx = g.y;
  const float U = minU[b * M_GT + j];
  // winner has d <= U*(1+3e-9) since w >= 1/(1+C_DEN); margins dwarf rounding
  float Rf = fminf(U * 1.000001f + 0.01f, 363.0f);
  int   Ri = (int)Rf + 1;
  float vmin = U;
  for (int yy = gy - Ri; yy <= gy + Ri; ++yy) {
    if ((unsigned)yy >= H_IMG) continue;
    float fdy = (float)(yy - gy);
    float dy2 = fdy * fdy;
    for (int xc = 0; xc <= 2 * Ri; xc += 64) {
      int xx = gx - Ri + xc + lane;
      if ((unsigned)xx < W_IMG) {
        float p   = prob[b * N_PIX + yy * W_IMG + xx];
        float p2  = p * p;
        float den = p2 * p2 + C_DEN;
        float w   = 1.0f / den;
        float fdx = (float)(xx - gx);
        float d   = __builtin_amdgcn_sqrtf(fmaf(fdx, fdx, dy2));
        vmin = fminf(vmin, fmaf(d, w, EPS * w));
      }
    }
  }
#pragma unroll
  for (int s = 1; s < 64; s <<= 1) vmin = fminf(vmin, __shfl_xor(vmin, s, 64));
  if (lane == 0) minU[b * M_GT + j] = vmin;
}

// ---------------- K3: finalize (deterministic fixed-order reductions) ----------------
__global__ __launch_bounds__(256) void whd_final(
    const float* __restrict__ minU,
    const float2* __restrict__ partials,
    float* __restrict__ out)
{
  const int tid  = threadIdx.x;
  const int lane = tid & 63;
  const int b    = tid >> 6;        // one wave per sample
  __shared__ float t1[NB], t2[NB];

  float s2 = 0.f;
#pragma unroll
  for (int u = 0; u < M_GT / 64; ++u) {
    float v = minU[b * M_GT + u * 64 + lane];
    v = fminf(fmaxf(v, 0.f), MAXD);
    s2 += v;
  }
  float s1 = 0.f, s0 = 0.f;
#pragma unroll
  for (int u = 0; u < TILES / 64; ++u) {
    float2 pp = partials[b * TILES + u * 64 + lane];
    s1 += pp.x; s0 += pp.y;
  }
#pragma unroll
  for (int m = 1; m < 64; m <<= 1) {
    s2 += __shfl_xor(s2, m, 64);
    s1 += __shfl_xor(s1, m, 64);
    s0 += __shfl_xor(s0, m, 64);
  }
  if (lane == 0) {
    t1[b] = s1 / (s0 + EPS);
    t2[b] = s2 / (float)M_GT;
  }
  __syncthreads();
  if (tid == 0) {
    float a = 0.f, c = 0.f;
    for (int i = 0; i < NB; ++i) { a += t1[i]; c += t2[i]; }
    out[0] = a * 0.25f + c * 0.25f;
  }
}

extern "C" void kernel_launch(void* const* d_in, const int* in_sizes, int n_in,
                              void* d_out, int out_size, void* d_ws, size_t ws_size,
                              hipStream_t stream) {
  const float* prob = (const float*)d_in[0];
  const int*   gt   = (const int*)d_in[1];

  float*  minU     = (float*)d_ws;
  float2* partials = (float2*)((char*)d_ws + (size_t)NB * M_GT * sizeof(float));

  whd_k1<<<dim3(TILES + 128, NB), 256, 0, stream>>>(prob, gt, minU, partials);
  whd_k2<<<dim3(M_GT / 4, NB), 256, 0, stream>>>(prob, gt, minU);
  whd_final<<<1, 256, 0, stream>>>(minU, partials, (float*)d_out);
}